// Round 1
// baseline (272.807 us; speedup 1.0000x reference)
//
#include <hip/hip_runtime.h>

constexpr int HID  = 1024;
constexpr int KDIR = 16;

// One block of 256 threads processes one row (1024 f32) at a time.
// Thread t owns elements [4t .. 4t+3]. Q rows for those elements (4x16 f32)
// are kept in registers for the whole block lifetime (reused across rows).
// Per row: compute 16 projection coefs + ||h||^2 via block reduction, then
// out = (h - sum_k c_k q_k) * rsqrt(1 - sum(c^2)/||h||^2).
__global__ __launch_bounds__(256, 4)
void probe_removal_kernel(const float* __restrict__ H,
                          const float* __restrict__ Q,
                          float* __restrict__ out,
                          int nrows)
{
    const int t    = threadIdx.x;   // 0..255
    const int lane = t & 63;
    const int wid  = t >> 6;

    // part[k][t]: per-thread partial of coef k. 260 = 256 + 4 pad so each row
    // is 1040 B (16B-aligned) and stage-2 float4 reads stay aligned.
    __shared__ __align__(16) float part[KDIR][260];
    __shared__ float4 fin4[4];   // final 16 coefs
    __shared__ float  s2w[4];    // per-wave ||h||^2 partials

    // ---- Q fragment -> registers (64 floats), loaded once per block ----
    float qr[4][KDIR];
    {
        const float4* Q4 = reinterpret_cast<const float4*>(Q);
        #pragma unroll
        for (int e = 0; e < 4; ++e) {
            #pragma unroll
            for (int j = 0; j < 4; ++j) {
                float4 a = Q4[(4*t + e)*4 + j];   // Q[(4t+e)][4j..4j+3]
                qr[e][4*j+0] = a.x; qr[e][4*j+1] = a.y;
                qr[e][4*j+2] = a.z; qr[e][4*j+3] = a.w;
            }
        }
    }

    for (int row = blockIdx.x; row < nrows; row += gridDim.x) {
        const float4 h4 = *reinterpret_cast<const float4*>(H + (size_t)row*HID + 4*t);

        // per-thread partial coefs c[k] = sum_e h[e]*Q[e][k], and ||h||^2 partial
        float c[KDIR];
        #pragma unroll
        for (int k = 0; k < KDIR; ++k) {
            c[k] = fmaf(h4.x, qr[0][k],
                   fmaf(h4.y, qr[1][k],
                   fmaf(h4.z, qr[2][k], h4.w * qr[3][k])));
        }
        float s2 = fmaf(h4.x,h4.x, fmaf(h4.y,h4.y, fmaf(h4.z,h4.z, h4.w*h4.w)));

        // stage 1: write partials. Addr = k*260 + t -> consecutive t hits
        // consecutive banks: conflict-free.
        #pragma unroll
        for (int k = 0; k < KDIR; ++k) part[k][t] = c[k];

        // ||h||^2: full-wave butterfly, then one slot per wave
        #pragma unroll
        for (int m = 32; m >= 1; m >>= 1) s2 += __shfl_xor(s2, m);
        if (lane == 0) s2w[wid] = s2;

        __syncthreads();   // barrier 1

        // stage 2: value v = t>>4 reduced by its 16-lane-aligned group.
        const int v = t >> 4, g = t & 15;
        const float4* prow = reinterpret_cast<const float4*>(&part[v][0]);
        float4 A = prow[g*4+0], B = prow[g*4+1], Cc = prow[g*4+2], D = prow[g*4+3];
        float sum = ((A.x+A.y)+(A.z+A.w)) + ((B.x+B.y)+(B.z+B.w))
                  + ((Cc.x+Cc.y)+(Cc.z+Cc.w)) + ((D.x+D.y)+(D.z+D.w));
        #pragma unroll
        for (int m = 8; m >= 1; m >>= 1) sum += __shfl_xor(sum, m);

        // read s2 partials here (between barriers) to avoid WAR on next iter
        const float s2tot = s2w[0] + s2w[1] + s2w[2] + s2w[3];

        if (g == 0) reinterpret_cast<float*>(fin4)[v] = sum;
        __syncthreads();   // barrier 2

        // broadcast-read the 16 final coefs
        float cf[KDIR];
        {
            float4 f0 = fin4[0], f1 = fin4[1], f2 = fin4[2], f3 = fin4[3];
            cf[0]=f0.x;  cf[1]=f0.y;  cf[2]=f0.z;  cf[3]=f0.w;
            cf[4]=f1.x;  cf[5]=f1.y;  cf[6]=f1.z;  cf[7]=f1.w;
            cf[8]=f2.x;  cf[9]=f2.y;  cf[10]=f2.z; cf[11]=f2.w;
            cf[12]=f3.x; cf[13]=f3.y; cf[14]=f3.z; cf[15]=f3.w;
        }

        float sumc2 = 0.f;
        #pragma unroll
        for (int k = 0; k < KDIR; ++k) sumc2 = fmaf(cf[k], cf[k], sumc2);

        // ||h_new||^2 = ||h||^2 - sum(c^2)  (orthonormal Q)
        const float scale = rsqrtf(1.0f - sumc2 / s2tot);

        float d0=0.f, d1=0.f, d2=0.f, d3=0.f;
        #pragma unroll
        for (int k = 0; k < KDIR; ++k) {
            d0 = fmaf(cf[k], qr[0][k], d0);
            d1 = fmaf(cf[k], qr[1][k], d1);
            d2 = fmaf(cf[k], qr[2][k], d2);
            d3 = fmaf(cf[k], qr[3][k], d3);
        }
        float4 o;
        o.x = (h4.x - d0) * scale;
        o.y = (h4.y - d1) * scale;
        o.z = (h4.z - d2) * scale;
        o.w = (h4.w - d3) * scale;
        *reinterpret_cast<float4*>(out + (size_t)row*HID + 4*t) = o;
    }
}

extern "C" void kernel_launch(void* const* d_in, const int* in_sizes, int n_in,
                              void* d_out, int out_size, void* d_ws, size_t ws_size,
                              hipStream_t stream) {
    const float* H  = (const float*)d_in[0];   // [8,4096,1024] f32
    const float* Q  = (const float*)d_in[1];   // [1024,16] f32
    float* outp     = (float*)d_out;
    const int nrows = in_sizes[0] / HID;       // 32768

    dim3 grid(2048), block(256);
    hipLaunchKernelGGL(probe_removal_kernel, grid, block, 0, stream,
                       H, Q, outp, nrows);
}

// Round 3
// 122.444 us; speedup vs baseline: 2.2280x; 2.2280x over previous
//
#include <hip/hip_runtime.h>

constexpr int HID  = 1024;
constexpr int KDIR = 16;
constexpr int NT   = 512;   // threads per block

typedef float f32x2 __attribute__((ext_vector_type(2)));  // native vector for nontemporal store

// Each thread owns 2 contiguous elements -> Q fragment is only 32 VGPRs,
// leaving total live pressure ~60 regs: compiler can keep Q register-resident
// at the 64-VGPR / 8-waves-per-SIMD occupancy tier (round-1 failure mode was
// Q re-loaded from global every row because 4 elems/thread needed 64 Q regs).
__global__ __launch_bounds__(NT)
void probe_removal_kernel(const float* __restrict__ H,
                          const float* __restrict__ Q,
                          float* __restrict__ out,
                          int nrows)
{
    const int t    = threadIdx.x;   // 0..511
    const int lane = t & 63;
    const int wid  = t >> 6;        // 0..7

    __shared__ __align__(16) float part[KDIR][NT + 8]; // stage-1 partials (pad keeps rows 16B-aligned)
    __shared__ __align__(16) float fin[KDIR];          // final coefs
    __shared__ float s2w[8];                           // per-wave ||h||^2 partials

    // ---- Q rows for this thread's 2 elements -> 32 registers, loaded once ----
    float q0[KDIR], q1[KDIR];
    {
        const float4* Q4 = reinterpret_cast<const float4*>(Q);
        #pragma unroll
        for (int j = 0; j < 4; ++j) {
            float4 a = Q4[(2*t + 0)*4 + j];   // Q[2t][4j..4j+3]
            q0[4*j+0]=a.x; q0[4*j+1]=a.y; q0[4*j+2]=a.z; q0[4*j+3]=a.w;
            float4 b = Q4[(2*t + 1)*4 + j];   // Q[2t+1][4j..4j+3]
            q1[4*j+0]=b.x; q1[4*j+1]=b.y; q1[4*j+2]=b.z; q1[4*j+3]=b.w;
        }
    }

    const float2* Hp = reinterpret_cast<const float2*>(H);
    f32x2*        Op = reinterpret_cast<f32x2*>(out);

    int row = blockIdx.x;
    float2 h = make_float2(0.f, 0.f);
    if (row < nrows) h = Hp[(size_t)row*(HID/2) + t];

    while (row < nrows) {
        // ---- prefetch next row into registers before any barrier ----
        const int nrow = row + (int)gridDim.x;
        float2 hn = make_float2(0.f, 0.f);
        if (nrow < nrows) hn = Hp[(size_t)nrow*(HID/2) + t];

        // per-thread partial coefs + ||h||^2 partial
        float c[KDIR];
        #pragma unroll
        for (int k = 0; k < KDIR; ++k) c[k] = fmaf(h.x, q0[k], h.y * q1[k]);
        float s2 = fmaf(h.x, h.x, h.y * h.y);

        // stage 1: conflict-free LDS writes (consecutive t -> consecutive banks)
        #pragma unroll
        for (int k = 0; k < KDIR; ++k) part[k][t] = c[k];

        // ||h||^2: full-wave butterfly, one slot per wave
        #pragma unroll
        for (int m = 32; m >= 1; m >>= 1) s2 += __shfl_xor(s2, m);
        if (lane == 0) s2w[wid] = s2;

        __syncthreads();   // barrier 1

        // stage 2: coef v reduced by its 32-thread group; strided float4 reads
        const int v = t >> 5, g = t & 31;
        const float4* prow = reinterpret_cast<const float4*>(&part[v][0]);
        float sum = 0.f;
        #pragma unroll
        for (int j = 0; j < 4; ++j) {
            float4 a = prow[j*32 + g];        // stride-512B: spreads banks
            sum += (a.x + a.y) + (a.z + a.w);
        }
        #pragma unroll
        for (int m = 16; m >= 1; m >>= 1) sum += __shfl_xor(sum, m);

        // read ||h||^2 partials between the barriers (no WAR with next iter)
        float s2tot = 0.f;
        #pragma unroll
        for (int wv = 0; wv < 8; ++wv) s2tot += s2w[wv];

        if (g == 0) fin[v] = sum;
        __syncthreads();   // barrier 2

        // epilogue: sumc2 + subtraction in one pass; fin[k] is an LDS
        // broadcast read (same addr across lanes -> free), short live range
        float d0 = 0.f, d1 = 0.f, sumc2 = 0.f;
        #pragma unroll
        for (int k = 0; k < KDIR; ++k) {
            const float cfk = fin[k];
            sumc2 = fmaf(cfk, cfk, sumc2);
            d0 = fmaf(cfk, q0[k], d0);
            d1 = fmaf(cfk, q1[k], d1);
        }
        // ||h_new||^2 = ||h||^2 - sum(c^2)  (orthonormal Q)
        const float scale = rsqrtf(1.0f - sumc2 / s2tot);

        f32x2 o;
        o.x = (h.x - d0) * scale;
        o.y = (h.y - d1) * scale;
        __builtin_nontemporal_store(o, &Op[(size_t)row*(HID/2) + t]);

        h = hn;
        row = nrow;
    }
}

extern "C" void kernel_launch(void* const* d_in, const int* in_sizes, int n_in,
                              void* d_out, int out_size, void* d_ws, size_t ws_size,
                              hipStream_t stream) {
    const float* H  = (const float*)d_in[0];   // [8,4096,1024] f32
    const float* Q  = (const float*)d_in[1];   // [1024,16] f32, orthonormal cols
    float* outp     = (float*)d_out;
    const int nrows = in_sizes[0] / HID;       // 32768

    dim3 grid(2048), block(NT);
    hipLaunchKernelGGL(probe_removal_kernel, grid, block, 0, stream,
                       H, Q, outp, nrows);
}

// Round 4
// 78.965 us; speedup vs baseline: 3.4548x; 1.5506x over previous
//
#include <hip/hip_runtime.h>
#include <hip/hip_bf16.h>

constexpr int HID = 1024;
constexpr int KD  = 16;    // probe directions
constexpr int NT  = 512;   // threads per block (8 waves)
constexpr int NW  = 8;     // waves per block
constexpr int TM  = 16;    // rows per tile

typedef short bf16x8 __attribute__((ext_vector_type(8)));   // MFMA A/B frag (8 bf16)
typedef float f32x4  __attribute__((ext_vector_type(4)));   // MFMA C/D frag

__device__ __forceinline__ short f2b(float x) {
    __hip_bfloat16 b = __float2bfloat16(x);
    return *reinterpret_cast<short*>(&b);
}

// Per 16-row tile:
//   coefs C[row][dir] = H_tile x Q           (mfma 16x16x32 bf16, K split over 8 waves)
//   out = (H - Dt) * scale,  Dt^T = Q x C^T  (mfma, K=16 zero-padded to 32)
//   scale[row] = rsqrt(1 - sum_k c_k^2 / ||h||^2)   (orthonormal Q)
// One __syncthreads per tile (double-buffered LDS reduction tile).
__global__ __launch_bounds__(NT, 4)   // cap VGPR at 128 -> 2 blocks (16 waves) per CU
void probe_removal_mfma(const float* __restrict__ H,
                        const float* __restrict__ Qf,
                        float* __restrict__ out,
                        int ntiles)
{
    const int t    = threadIdx.x;
    const int lane = t & 63;
    const int w    = t >> 6;       // wave 0..7: owns hidden-slice [w*128, w*128+128)
    const int r    = lane & 15;    // row-within-tile (A-layout M, C-layout N)
    const int q    = lane >> 4;    // quad-group 0..3 (k/row chunk selector)

    // LDS reduction tiles: red[buf][wave][row][dir(16)+pad4]  (pad: bank spread, keeps 16B align)
    __shared__ __align__(16) float red[2][NW][TM][20];
    __shared__ float s2red[2][NW][TM];

    // ---------- per-block setup: Q fragments (register-resident) ----------
    // coef GEMM B-frag: B[k][n=dir], lane holds k = w*128+kt*32+q*8+i, n = r
    bf16x8 bq[4];
    #pragma unroll
    for (int kt = 0; kt < 4; ++kt) {
        #pragma unroll
        for (int i = 0; i < 8; ++i) {
            const int k = w*128 + kt*32 + q*8 + i;
            bq[kt][i] = f2b(Qf[k*KD + r]);
        }
    }
    // epilogue GEMM A-frag: A[m=col][k=dir(pad to 32)], lane holds m = r, k = q*8+i
    bf16x8 aq[8];
    #pragma unroll
    for (int j = 0; j < 8; ++j) {
        if (q < 2) {
            const float* src = Qf + (w*128 + j*16 + r)*KD + q*8;
            const float4 x = *reinterpret_cast<const float4*>(src);
            const float4 y = *reinterpret_cast<const float4*>(src + 4);
            aq[j][0]=f2b(x.x); aq[j][1]=f2b(x.y); aq[j][2]=f2b(x.z); aq[j][3]=f2b(x.w);
            aq[j][4]=f2b(y.x); aq[j][5]=f2b(y.y); aq[j][6]=f2b(y.z); aq[j][7]=f2b(y.w);
        } else {                       // dirs 16..31 are zero padding
            #pragma unroll
            for (int i = 0; i < 8; ++i) aq[j][i] = 0;
        }
    }

    int buf = 0;
    for (int tile = blockIdx.x; tile < ntiles; tile += gridDim.x) {
        const size_t rowbase = (size_t)tile*TM + r;
        const float* hrow = H + rowbase*HID + w*128;

        // ---- load H slice (A-layout), accumulate ||h||^2, convert to bf16 ----
        float s2 = 0.f;
        bf16x8 af[4];
        #pragma unroll
        for (int kt = 0; kt < 4; ++kt) {
            const float4 x = *reinterpret_cast<const float4*>(hrow + kt*32 + q*8);
            const float4 y = *reinterpret_cast<const float4*>(hrow + kt*32 + q*8 + 4);
            s2 = fmaf(x.x,x.x, fmaf(x.y,x.y, fmaf(x.z,x.z, fmaf(x.w,x.w, s2))));
            s2 = fmaf(y.x,y.x, fmaf(y.y,y.y, fmaf(y.z,y.z, fmaf(y.w,y.w, s2))));
            af[kt][0]=f2b(x.x); af[kt][1]=f2b(x.y); af[kt][2]=f2b(x.z); af[kt][3]=f2b(x.w);
            af[kt][4]=f2b(y.x); af[kt][5]=f2b(y.y); af[kt][6]=f2b(y.z); af[kt][7]=f2b(y.w);
        }
        // combine the 4 lanes sharing this row (same r, different q)
        s2 += __shfl_xor(s2, 16);
        s2 += __shfl_xor(s2, 32);

        // ---- coef GEMM: partial C[row][dir] for this wave's 128-wide K slice ----
        f32x4 acc = {0.f, 0.f, 0.f, 0.f};
        #pragma unroll
        for (int kt = 0; kt < 4; ++kt)
            acc = __builtin_amdgcn_mfma_f32_16x16x32_bf16(af[kt], bq[kt], acc, 0, 0, 0);

        // C-layout: lane holds C[row = q*4+i][dir = r] -> store as red[...][row][dir]
        #pragma unroll
        for (int i = 0; i < 4; ++i) red[buf][w][q*4 + i][r] = acc[i];
        if (q == 0) s2red[buf][w][r] = s2;

        __syncthreads();   // the only barrier per tile

        // ---- cross-wave reduce; build epilogue B-frag B[k=dir][n=row]: lane (q<2) holds
        //      dirs q*8..q*8+7 of row r (dirs 16..31 zero-padded) ----
        float cf[8] = {0,0,0,0,0,0,0,0};
        if (q < 2) {
            #pragma unroll
            for (int w2 = 0; w2 < NW; ++w2) {
                const float* base = &red[buf][w2][r][q*8];
                const float4 a = *reinterpret_cast<const float4*>(base);
                const float4 b = *reinterpret_cast<const float4*>(base + 4);
                cf[0]+=a.x; cf[1]+=a.y; cf[2]+=a.z; cf[3]+=a.w;
                cf[4]+=b.x; cf[5]+=b.y; cf[6]+=b.z; cf[7]+=b.w;
            }
        }
        float s2tot = 0.f;
        #pragma unroll
        for (int w2 = 0; w2 < NW; ++w2) s2tot += s2red[buf][w2][r];

        // sum_k c_k^2 for row r: partial over this lane's 8 dirs, combine q-groups
        float sc2 = 0.f;
        #pragma unroll
        for (int i = 0; i < 8; ++i) sc2 = fmaf(cf[i], cf[i], sc2);
        sc2 += __shfl_xor(sc2, 16);
        sc2 += __shfl_xor(sc2, 32);

        const float scale = rsqrtf(fmaxf(1.0f - sc2 / s2tot, 1e-20f));

        bf16x8 pb;
        #pragma unroll
        for (int i = 0; i < 8; ++i) pb[i] = f2b(cf[i]);   // q>=2 lanes: zeros (K padding)

        // ---- epilogue: Dt = Q x C^T per 16-col tile; out = (h - Dt)*scale ----
        float* orow = out + rowbase*HID + w*128;
        const f32x4 zero4 = {0.f, 0.f, 0.f, 0.f};
        #pragma unroll
        for (int j = 0; j < 8; ++j) {
            f32x4 d = __builtin_amdgcn_mfma_f32_16x16x32_bf16(aq[j], pb, zero4, 0, 0, 0);
            // D layout: lane holds rows-of-out = r, cols = w*128 + j*16 + q*4 + {0..3}
            const float4 hx = *reinterpret_cast<const float4*>(hrow + j*16 + q*4); // L2-hot re-read
            f32x4 o;
            o[0] = (hx.x - d[0]) * scale;
            o[1] = (hx.y - d[1]) * scale;
            o[2] = (hx.z - d[2]) * scale;
            o[3] = (hx.w - d[3]) * scale;
            __builtin_nontemporal_store(o, reinterpret_cast<f32x4*>(orow + j*16 + q*4));
        }

        buf ^= 1;   // double-buffered reduction tile -> no second barrier needed
    }
}

extern "C" void kernel_launch(void* const* d_in, const int* in_sizes, int n_in,
                              void* d_out, int out_size, void* d_ws, size_t ws_size,
                              hipStream_t stream) {
    const float* H  = (const float*)d_in[0];   // [8,4096,1024] f32
    const float* Qf = (const float*)d_in[1];   // [1024,16] f32, orthonormal cols
    float* outp     = (float*)d_out;
    const int nrows  = in_sizes[0] / HID;      // 32768
    const int ntiles = nrows / TM;             // 2048

    // 512 blocks x 8 waves = 4096 waves = exactly 2 blocks/CU x 256 CUs resident
    dim3 grid(512), block(NT);
    hipLaunchKernelGGL(probe_removal_mfma, grid, block, 0, stream,
                       H, Qf, outp, ntiles);
}

// Round 5
// 66.013 us; speedup vs baseline: 4.1326x; 1.1962x over previous
//
#include <hip/hip_runtime.h>
#include <hip/hip_bf16.h>

constexpr int HID = 1024;
constexpr int KD  = 16;    // probe directions
constexpr int NT  = 512;   // threads per block (8 waves)
constexpr int NW  = 8;     // waves per block
constexpr int TM  = 16;    // rows per tile

typedef short bf16x8 __attribute__((ext_vector_type(8)));   // MFMA A/B frag
typedef float f32x4  __attribute__((ext_vector_type(4)));   // MFMA C/D frag
typedef unsigned int uint32_tt;

__device__ __forceinline__ short f2b(float x) {
    __hip_bfloat16 b = __float2bfloat16(x);
    return *reinterpret_cast<short*>(&b);
}

// All global I/O is fully coalesced (1KB-contiguous per wave instruction);
// LDS does the layout conversion to/from MFMA fragment order.
//   H-tile: bf16 [16][1024], 16B chunks XOR-swizzled by (row&7)  -> conflict-free b128 reads
//   out-tile: f32, compacted per half-pass [16][8*68+4]          -> conflict-free, full-line stores
__global__ __launch_bounds__(NT, 4)   // 4 waves/SIMD -> VGPR<=128, 2 blocks/CU
void probe_removal_mfma2(const float* __restrict__ H,
                         const float* __restrict__ Qf,
                         float* __restrict__ out,
                         int ntiles)
{
    const int t    = threadIdx.x;
    const int lane = t & 63;
    const int w    = t >> 6;       // wave: owns hidden-slice [w*128, w*128+128)
    const int r    = lane & 15;
    const int q    = lane >> 4;

    __shared__ __align__(16) unsigned short Ht[TM][HID];     // 32 KB, swizzled
    __shared__ __align__(16) float red[NW][TM][20];          // 10.2 KB coef partials [wave][row][dir]
    __shared__ float s2red[NW][TM];                          // ||h||^2 partials
    __shared__ __align__(16) float outl[TM][NW*68 + 4];      // 35 KB out staging (row stride 548 dw)

    char* HtB = reinterpret_cast<char*>(&Ht[0][0]);

    // ---------- Q fragments (register-resident, loaded once) ----------
    // coef GEMM B-frag: B[k][n=dir=r], k = w*128+kt*32+q*8+i
    bf16x8 bq[4];
    #pragma unroll
    for (int kt = 0; kt < 4; ++kt)
        #pragma unroll
        for (int i = 0; i < 8; ++i)
            bq[kt][i] = f2b(Qf[(w*128 + kt*32 + q*8 + i)*KD + r]);
    // epilogue GEMM A-frag: A[m=col=r][k=dir(pad to 32)]
    bf16x8 aq[8];
    #pragma unroll
    for (int j = 0; j < 8; ++j) {
        if (q < 2) {
            const float* src = Qf + (w*128 + j*16 + r)*KD + q*8;
            const float4 x = *reinterpret_cast<const float4*>(src);
            const float4 y = *reinterpret_cast<const float4*>(src + 4);
            aq[j][0]=f2b(x.x); aq[j][1]=f2b(x.y); aq[j][2]=f2b(x.z); aq[j][3]=f2b(x.w);
            aq[j][4]=f2b(y.x); aq[j][5]=f2b(y.y); aq[j][6]=f2b(y.z); aq[j][7]=f2b(y.w);
        } else {
            #pragma unroll
            for (int i = 0; i < 8; ++i) aq[j][i] = 0;
        }
    }

    for (int tile = blockIdx.x; tile < ntiles; tile += gridDim.x) {
        const float* Hbase = H + (size_t)tile*TM*HID;

        // ---- L: coalesced global load -> bf16 -> swizzled LDS ----
        #pragma unroll
        for (int j = 0; j < 8; ++j) {
            const int f4 = t + j*NT;                 // float4 idx in tile, wave-contiguous
            const float4 v = reinterpret_cast<const float4*>(Hbase)[f4];
            const int rr  = f4 >> 8;                 // row (256 float4/row)
            const int c4  = f4 & 255;
            const int c16 = c4 >> 1, half = c4 & 1;  // 16B chunk + 8B half
            short4 b;
            b.x = f2b(v.x); b.y = f2b(v.y); b.z = f2b(v.z); b.w = f2b(v.w);
            *reinterpret_cast<short4*>(HtB + rr*2048 + ((c16 ^ (rr & 7))*16) + half*8) = b;
        }
        __syncthreads();   // b1

        // ---- C: A-frags from LDS, coef MFMA, ||h||^2 in VALU from bf16 ----
        bf16x8 af[4];
        #pragma unroll
        for (int kt = 0; kt < 4; ++kt) {
            const int c16 = w*16 + kt*4 + q;
            af[kt] = *reinterpret_cast<const bf16x8*>(HtB + r*2048 + ((c16 ^ (r & 7))*16));
        }
        f32x4 acc = {0.f, 0.f, 0.f, 0.f};
        #pragma unroll
        for (int kt = 0; kt < 4; ++kt)
            acc = __builtin_amdgcn_mfma_f32_16x16x32_bf16(af[kt], bq[kt], acc, 0, 0, 0);

        float s2 = 0.f;
        #pragma unroll
        for (int kt = 0; kt < 4; ++kt) {
            const uint4 u = __builtin_bit_cast(uint4, af[kt]);
            #pragma unroll
            for (int e = 0; e < 4; ++e) {
                const unsigned int ue = (&u.x)[e];
                const float lo = __uint_as_float(ue << 16);
                const float hi = __uint_as_float(ue & 0xffff0000u);
                s2 = fmaf(lo, lo, fmaf(hi, hi, s2));
            }
        }
        s2 += __shfl_xor(s2, 16);
        s2 += __shfl_xor(s2, 32);

        #pragma unroll
        for (int i = 0; i < 4; ++i) red[w][q*4 + i][r] = acc[i];   // C[m=q*4+i][n=dir=r]
        if (q == 0) s2red[w][r] = s2;
        __syncthreads();   // b2

        // ---- R: cross-wave reduce -> coefs, scale, pb frag ----
        float cf[8] = {0,0,0,0,0,0,0,0};
        if (q < 2) {
            #pragma unroll
            for (int w2 = 0; w2 < NW; ++w2) {
                const float4 a  = *reinterpret_cast<const float4*>(&red[w2][r][q*8]);
                const float4 bb = *reinterpret_cast<const float4*>(&red[w2][r][q*8 + 4]);
                cf[0]+=a.x;  cf[1]+=a.y;  cf[2]+=a.z;  cf[3]+=a.w;
                cf[4]+=bb.x; cf[5]+=bb.y; cf[6]+=bb.z; cf[7]+=bb.w;
            }
        }
        float s2tot = 0.f;
        #pragma unroll
        for (int w2 = 0; w2 < NW; ++w2) s2tot += s2red[w2][r];   // broadcast reads

        float sc2 = 0.f;
        #pragma unroll
        for (int i = 0; i < 8; ++i) sc2 = fmaf(cf[i], cf[i], sc2);
        sc2 += __shfl_xor(sc2, 16);
        sc2 += __shfl_xor(sc2, 32);
        const float scale = rsqrtf(fmaxf(1.0f - sc2 / s2tot, 1e-20f));

        bf16x8 pb;   // B[k=dir][n=row=r]; q>=2 lanes hold K-pad zeros
        #pragma unroll
        for (int i = 0; i < 8; ++i) pb[i] = f2b(cf[i]);

        // ---- E+S: two half passes (epilogue MFMA -> outl -> coalesced store) ----
        const f32x4 zero4 = {0.f, 0.f, 0.f, 0.f};
        #pragma unroll
        for (int pass = 0; pass < 2; ++pass) {
            #pragma unroll
            for (int jj = 0; jj < 4; ++jj) {
                const int j = pass*4 + jj;
                f32x4 d = __builtin_amdgcn_mfma_f32_16x16x32_bf16(aq[j], pb, zero4, 0, 0, 0);
                // h (bf16) re-read from LDS at the C-layout positions
                const int c16 = w*16 + j*2 + (q >> 1);
                const uint2 hu = *reinterpret_cast<const uint2*>(
                    HtB + r*2048 + ((c16 ^ (r & 7))*16) + (q & 1)*8);
                f32x4 o;
                o[0] = (__uint_as_float(hu.x << 16)         - d[0]) * scale;
                o[1] = (__uint_as_float(hu.x & 0xffff0000u) - d[1]) * scale;
                o[2] = (__uint_as_float(hu.y << 16)         - d[2]) * scale;
                o[3] = (__uint_as_float(hu.y & 0xffff0000u) - d[3]) * scale;
                *reinterpret_cast<f32x4*>(&outl[r][w*68 + jj*16 + q*4]) = o;
            }
            __syncthreads();   // outl ready

            // coalesced store of this half: full 128B lines only
            #pragma unroll
            for (int p = 0; p < 4; ++p) {
                const int flat = t + p*NT;           // float4 idx in half-tile
                const int rr  = flat >> 7;
                const int idx = flat & 127;
                const int ww  = idx >> 4, i4 = idx & 15;
                const float4 v = *reinterpret_cast<const float4*>(&outl[rr][ww*68 + i4*4]);
                const f32x4 vv = {v.x, v.y, v.z, v.w};
                float* dst = out + ((size_t)tile*TM + rr)*HID + ww*128 + pass*64 + i4*4;
                __builtin_nontemporal_store(vv, reinterpret_cast<f32x4*>(dst));
            }
            __syncthreads();   // outl free for next pass / Ht free for next tile
        }
    }
}

extern "C" void kernel_launch(void* const* d_in, const int* in_sizes, int n_in,
                              void* d_out, int out_size, void* d_ws, size_t ws_size,
                              hipStream_t stream) {
    const float* H  = (const float*)d_in[0];   // [8,4096,1024] f32
    const float* Qf = (const float*)d_in[1];   // [1024,16] f32, orthonormal cols
    float* outp     = (float*)d_out;
    const int nrows  = in_sizes[0] / HID;      // 32768
    const int ntiles = nrows / TM;             // 2048

    dim3 grid(512), block(NT);                 // 2 blocks/CU resident, 4 tiles/block
    hipLaunchKernelGGL(probe_removal_mfma2, grid, block, 0, stream,
                       H, Qf, outp, ntiles);
}